// Round 1
// baseline (3098.563 us; speedup 1.0000x reference)
//
#include <hip/hip_runtime.h>
#include <cstdint>

// ---------------------------------------------------------------------------
// SFA fusion pipeline, fp32 baseline.
//   B=4, C=128, H=W=180, NC=10, Q=5 -> feat_in=306, hid=64
// Stages:
//   1. weight transpose  w[Cout][Cin*9] -> wT[Cin*9][Cout]   (coalesced staging)
//   2. heatmap transpose+sigmoid+L2norm  -> hpn, hin  (B,10,H,W)
//   3. dual cost volumes  -> cp, ci  (B,25,H,W)
//   4. conv1 306->64 + relu  (virtual concat [pts, cp, img, ci])  -> h
//   5. conv2 64->4 + tanh*5  -> flow
//   6. grid_sample border/align_corners -> fused_in = [aligned_i, aligned_p] (B,256,H,W)
//   7. g1 256->128 + relu -> g1o
//   8. g2 128->128 + bias -> d_out
// ---------------------------------------------------------------------------

constexpr int H = 180, W = 180;
constexpr int HW = H * W;

// workspace offsets in floats (h aliases hpn/hin region, both dead by conv1)
constexpr size_t OFF_HPN  = 0;                       // 1,296,000
constexpr size_t OFF_HIN  = 1296000;                 // 1,296,000
constexpr size_t OFF_H    = 0;                       // 8,294,400 (aliases hpn+hin)
constexpr size_t OFF_CP   = 8294400;                 // 3,240,000
constexpr size_t OFF_CI   = OFF_CP + 3240000;        // 11,534,400
constexpr size_t OFF_FLOW = OFF_CI + 3240000;        // 14,774,400
constexpr size_t OFF_FUSED= OFF_FLOW + 518400;       // 15,292,800
constexpr size_t OFF_G1   = OFF_FUSED + 33177600;    // 48,470,400
constexpr size_t OFF_WT1  = OFF_G1 + 16588800;       // 65,059,200
constexpr size_t OFF_WTG1 = OFF_WT1 + 176256;
constexpr size_t OFF_WTG2 = OFF_WTG1 + 294912;
// total = 65,677,824 floats = 250.5 MiB

// ---------------------------------------------------------------------------
// 1. weight transform: w[oc][c][ky][kx] -> wT[(c*9+ky*3+kx)*Cout + oc]
__global__ __launch_bounds__(256) void wt_kernel(const float* __restrict__ w,
                                                 float* __restrict__ wT,
                                                 int Cin, int Cout, int total) {
    int idx = blockIdx.x * 256 + threadIdx.x;
    if (idx >= total) return;
    int oc = idx % Cout;
    int k  = idx / Cout;
    wT[idx] = w[(size_t)oc * Cin * 9 + k];
}

// ---------------------------------------------------------------------------
// 2. heatmap prep: transpose (b,c,w,h)->(b,c,h,w), sigmoid, L2-normalize over c
__global__ __launch_bounds__(256) void prep_heatmaps(
    const float* __restrict__ hm_pts, const float* __restrict__ hm_img,
    float* __restrict__ hpn, float* __restrict__ hin, int B, int total) {
    int id = blockIdx.x * 256 + threadIdx.x;
    if (id >= total) return;                 // total = 2*B*HW
    int w = id % W; int r = id / W;
    int h = r % H;  r /= H;
    int b = r % B;  int tsel = r / B;
    const float* src = tsel ? hm_img : hm_pts;
    float* dst = tsel ? hin : hpn;
    float v[10]; float ss = 0.f;
#pragma unroll
    for (int c = 0; c < 10; ++c) {
        float x = src[((size_t)(b * 10 + c) * W + w) * H + h];  // transposed read
        float s = 1.f / (1.f + expf(-x));
        v[c] = s; ss += s * s;
    }
    float inv = 1.f / fmaxf(sqrtf(ss), 1e-12f);
#pragma unroll
    for (int c = 0; c < 10; ++c)
        dst[(size_t)(b * 10 + c) * HW + h * W + w] = v[c] * inv;
}

// ---------------------------------------------------------------------------
// 3. dual cost volumes: cp = <hpn(x), hin(x+d)>, ci = <hin(x), hpn(x+d)>
__global__ __launch_bounds__(256) void cost_volume_kernel(
    const float* __restrict__ hpn, const float* __restrict__ hin,
    float* __restrict__ cp, float* __restrict__ ci, int B, int total) {
    int id = blockIdx.x * 256 + threadIdx.x;
    if (id >= total) return;                 // total = B*HW
    int w = id % W; int r = id / W;
    int h = r % H;  int b = r / H;
    float hp_l[10], hi_l[10];
    size_t base = (size_t)b * 10 * HW + h * W + w;
#pragma unroll
    for (int c = 0; c < 10; ++c) {
        hp_l[c] = hpn[base + (size_t)c * HW];
        hi_l[c] = hin[base + (size_t)c * HW];
    }
    int k = 0;
    for (int dy = 0; dy < 5; ++dy)
        for (int dx = 0; dx < 5; ++dx, ++k) {
            int yy = h + dy - 2, xx = w + dx - 2;
            float ap = 0.f, ai = 0.f;
            if (yy >= 0 && yy < H && xx >= 0 && xx < W) {
                size_t nb = (size_t)b * 10 * HW + yy * W + xx;
#pragma unroll
                for (int c = 0; c < 10; ++c) {
                    ap = fmaf(hp_l[c], hin[nb + (size_t)c * HW], ap);
                    ai = fmaf(hi_l[c], hpn[nb + (size_t)c * HW], ai);
                }
            }
            size_t o = (size_t)(b * 25 + k) * HW + h * W + w;
            cp[o] = ap; ci[o] = ai;
        }
}

// ---------------------------------------------------------------------------
// virtual concat fetch for conv1: [pts(128), cp(25), img(128), ci(25)]
__device__ __forceinline__ float fetch_concat(
    const float* p0, const float* p1, const float* p2, const float* p3,
    int b, int c, int y, int x) {
    int sp = y * W + x;
    if (c < 128) return p0[(size_t)(b * 128 + c) * HW + sp];
    if (c < 153) return p1[(size_t)(b * 25 + (c - 128)) * HW + sp];
    if (c < 281) return p2[(size_t)(b * 128 + (c - 153)) * HW + sp];
    return p3[(size_t)(b * 25 + (c - 281)) * HW + sp];
}

// ---------------------------------------------------------------------------
// generic 3x3 SAME conv, fp32.  Block: 8x16 pixel tile x 64 oc, 256 threads.
// Micro-tile per thread: 8 px (x-consecutive) x 4 oc.  K-chunk: 4 channels.
template <int MODE, bool RELU>
__global__ __launch_bounds__(256, 4) void conv3x3_kernel(
    const float* __restrict__ inA, const float* __restrict__ inB,
    const float* __restrict__ inC, const float* __restrict__ inD,
    const float* __restrict__ wT,   // [Cin*9][Cout]
    const float* __restrict__ bias, float* __restrict__ out,
    int Cin, int Cout, int B) {
    __shared__ __align__(16) float s_in[4][10][20];
    __shared__ __align__(16) float s_w[36][64];

    const int t   = threadIdx.x;
    const int tn  = t & 15;         // oc group: 4 oc each
    const int tm  = t >> 4;         // pixel group: 8 px each
    const int my  = tm >> 1;
    const int mx0 = (tm & 1) * 8;
    const int nt  = Cout >> 6;
    const int b   = blockIdx.z / nt;
    const int oc0 = (blockIdx.z % nt) << 6;
    const int ty0 = blockIdx.y * 8, tx0 = blockIdx.x * 16;

    float acc[8][4];
#pragma unroll
    for (int i = 0; i < 8; ++i)
#pragma unroll
        for (int j = 0; j < 4; ++j) acc[i][j] = 0.f;

    const int nChunks = (Cin + 3) >> 2;
    for (int chunk = 0; chunk < nChunks; ++chunk) {
        const int c0 = chunk << 2;
        __syncthreads();
        // stage input halo tile: 4 ch x 10 rows x 18 cols
        for (int u = t; u < 720; u += 256) {
            int ch = u / 180, rem = u % 180;
            int row = rem / 18, col = rem % 18;
            int gy = ty0 + row - 1, gx = tx0 + col - 1;
            int c = c0 + ch;
            float v = 0.f;
            if (c < Cin && gy >= 0 && gy < H && gx >= 0 && gx < W) {
                if (MODE == 0)
                    v = inA[(size_t)(b * Cin + c) * HW + gy * W + gx];
                else
                    v = fetch_concat(inA, inB, inC, inD, b, c, gy, gx);
            }
            s_in[ch][row][col] = v;
        }
        // stage weights: 36 k x 64 oc (coalesced from wT)
#pragma unroll
        for (int i = 0; i < 9; ++i) {
            int idx = i * 256 + t;
            int k = idx >> 6, oc = idx & 63;
            int c = c0 + k / 9;
            float v = 0.f;
            if (c < Cin) v = wT[(size_t)(c * 9 + k % 9) * Cout + oc0 + oc];
            s_w[k][oc] = v;
        }
        __syncthreads();
        // compute
#pragma unroll
        for (int ch = 0; ch < 4; ++ch) {
#pragma unroll
            for (int ky = 0; ky < 3; ++ky) {
                float a[10];
#pragma unroll
                for (int j = 0; j < 10; ++j) a[j] = s_in[ch][my + ky][mx0 + j];
#pragma unroll
                for (int kx = 0; kx < 3; ++kx) {
                    const float4 w4 =
                        *(const float4*)(&s_w[ch * 9 + ky * 3 + kx][tn * 4]);
#pragma unroll
                    for (int px = 0; px < 8; ++px) {
                        acc[px][0] = fmaf(a[px + kx], w4.x, acc[px][0]);
                        acc[px][1] = fmaf(a[px + kx], w4.y, acc[px][1]);
                        acc[px][2] = fmaf(a[px + kx], w4.z, acc[px][2]);
                        acc[px][3] = fmaf(a[px + kx], w4.w, acc[px][3]);
                    }
                }
            }
        }
    }
    // epilogue: bias (+relu), vectorized float4 stores
    const int y = ty0 + my;
    if (y < H) {
#pragma unroll
        for (int o = 0; o < 4; ++o) {
            const int oc = oc0 + tn * 4 + o;
            const float bs = bias[oc];
            float* op = out + (size_t)(b * Cout + oc) * HW + y * W + tx0 + mx0;
#pragma unroll
            for (int q = 0; q < 2; ++q) {
                int xb = tx0 + mx0 + q * 4;
                if (xb < W) {
                    float4 v;
                    v.x = acc[q * 4 + 0][o] + bs;
                    v.y = acc[q * 4 + 1][o] + bs;
                    v.z = acc[q * 4 + 2][o] + bs;
                    v.w = acc[q * 4 + 3][o] + bs;
                    if (RELU) {
                        v.x = fmaxf(v.x, 0.f); v.y = fmaxf(v.y, 0.f);
                        v.z = fmaxf(v.z, 0.f); v.w = fmaxf(v.w, 0.f);
                    }
                    *(float4*)(op + q * 4) = v;
                }
            }
        }
    }
}

// ---------------------------------------------------------------------------
// 5. conv2 64->4 + tanh*5 -> flow.  Block: 16x16 pixels.
__global__ __launch_bounds__(256) void conv_flow_kernel(
    const float* __restrict__ hbuf, const float* __restrict__ fw2,
    const float* __restrict__ fb2, float* __restrict__ flow, int B) {
    __shared__ __align__(16) float s_in[8][18][20];
    __shared__ __align__(16) float s_w[72][4];
    const int t = threadIdx.x;
    const int px = t & 15, py = t >> 4;
    const int b = blockIdx.z;
    const int ty0 = blockIdx.y * 16, tx0 = blockIdx.x * 16;
    float acc[4] = {0.f, 0.f, 0.f, 0.f};
    for (int chunk = 0; chunk < 8; ++chunk) {
        int c0 = chunk * 8;
        __syncthreads();
        for (int u = t; u < 8 * 18 * 18; u += 256) {
            int ch = u / 324, rem = u % 324;
            int row = rem / 18, col = rem % 18;
            int gy = ty0 + row - 1, gx = tx0 + col - 1;
            float v = 0.f;
            if (gy >= 0 && gy < H && gx >= 0 && gx < W)
                v = hbuf[(size_t)(b * 64 + c0 + ch) * HW + gy * W + gx];
            s_in[ch][row][col] = v;
        }
        for (int u = t; u < 288; u += 256) {
            int k = u >> 2, o = u & 3;
            int ch = k / 9, kk = k % 9;
            s_w[k][o] = fw2[(size_t)(o * 64 + c0 + ch) * 9 + kk];
        }
        __syncthreads();
#pragma unroll
        for (int ch = 0; ch < 8; ++ch)
#pragma unroll
            for (int ky = 0; ky < 3; ++ky)
#pragma unroll
                for (int kx = 0; kx < 3; ++kx) {
                    float a = s_in[ch][py + ky][px + kx];
                    const float4 w4 =
                        *(const float4*)(&s_w[ch * 9 + ky * 3 + kx][0]);
                    acc[0] = fmaf(a, w4.x, acc[0]);
                    acc[1] = fmaf(a, w4.y, acc[1]);
                    acc[2] = fmaf(a, w4.z, acc[2]);
                    acc[3] = fmaf(a, w4.w, acc[3]);
                }
    }
    int y = ty0 + py, x = tx0 + px;
    if (y < H && x < W) {
#pragma unroll
        for (int o = 0; o < 4; ++o)
            flow[(size_t)(b * 4 + o) * HW + y * W + x] =
                tanhf(acc[o] + fb2[o]) * 5.0f;
    }
}

// ---------------------------------------------------------------------------
// 6. grid sample (bilinear, border, align_corners) -> fused_in [aligned_i, aligned_p]
__global__ __launch_bounds__(256) void grid_sample_kernel(
    const float* __restrict__ pts, const float* __restrict__ img,
    const float* __restrict__ flow, float* __restrict__ fused, int B, int total) {
    int id = blockIdx.x * 256 + threadIdx.x;
    if (id >= total) return;                 // total = 32*B*HW
    int w = id % W; int r = id / W;
    int h = r % H;  r /= H;
    int b = r % B;  int q = r / B;           // q: 0..15 img chunks, 16..31 pts chunks
    const bool is_img = q < 16;
    const int cb = (is_img ? q : q - 16) * 8;
    const float* src = is_img ? img : pts;
    const int fo = is_img ? 2 : 0;
    size_t fbase = (size_t)b * 4 * HW + h * W + w;
    float sx = (float)w + flow[fbase + (size_t)fo * HW];
    float sy = (float)h + flow[fbase + (size_t)(fo + 1) * HW];
    sx = fminf(fmaxf(sx, 0.f), (float)(W - 1));
    sy = fminf(fmaxf(sy, 0.f), (float)(H - 1));
    float x0f = floorf(sx), y0f = floorf(sy);
    float x1f = fminf(x0f + 1.f, (float)(W - 1));
    float y1f = fminf(y0f + 1.f, (float)(H - 1));
    float wx = sx - x0f, wy = sy - y0f;
    int x0 = (int)x0f, x1 = (int)x1f, y0 = (int)y0f, y1 = (int)y1f;
    float w00 = (1.f - wx) * (1.f - wy), w01 = wx * (1.f - wy);
    float w10 = (1.f - wx) * wy,         w11 = wx * wy;
    const float* sb = src + (size_t)b * 128 * HW;
    float* ob = fused + (size_t)b * 256 * HW +
                (size_t)((is_img ? 0 : 128) + cb) * HW + h * W + w;
#pragma unroll
    for (int j = 0; j < 8; ++j) {
        const float* p = sb + (size_t)(cb + j) * HW;
        float v = p[y0 * W + x0] * w00 + p[y0 * W + x1] * w01 +
                  p[y1 * W + x0] * w10 + p[y1 * W + x1] * w11;
        ob[(size_t)j * HW] = v;
    }
}

// ---------------------------------------------------------------------------
extern "C" void kernel_launch(void* const* d_in, const int* in_sizes, int n_in,
                              void* d_out, int out_size, void* d_ws, size_t ws_size,
                              hipStream_t stream) {
    const float* pts  = (const float*)d_in[0];
    const float* img  = (const float*)d_in[1];
    const float* hm_p = (const float*)d_in[2];
    const float* hm_i = (const float*)d_in[3];
    const float* fw1  = (const float*)d_in[4];
    const float* fb1  = (const float*)d_in[5];
    const float* fw2  = (const float*)d_in[6];
    const float* fb2  = (const float*)d_in[7];
    const float* gw1  = (const float*)d_in[8];
    const float* gb1  = (const float*)d_in[9];
    const float* gw2  = (const float*)d_in[10];
    const float* gb2  = (const float*)d_in[11];
    float* ws = (float*)d_ws;
    const int B = in_sizes[0] / (128 * HW);   // 4

    float* hpn   = ws + OFF_HPN;
    float* hin   = ws + OFF_HIN;
    float* hbuf  = ws + OFF_H;
    float* cp    = ws + OFF_CP;
    float* ci    = ws + OFF_CI;
    float* flow  = ws + OFF_FLOW;
    float* fused = ws + OFF_FUSED;
    float* g1o   = ws + OFF_G1;
    float* wT1   = ws + OFF_WT1;
    float* wTg1  = ws + OFF_WTG1;
    float* wTg2  = ws + OFF_WTG2;

    // 1. weight transforms (tiny, run every call — graph-safe)
    {
        int n1 = 306 * 9 * 64;
        wt_kernel<<<(n1 + 255) / 256, 256, 0, stream>>>(fw1, wT1, 306, 64, n1);
        int n2 = 256 * 9 * 128;
        wt_kernel<<<(n2 + 255) / 256, 256, 0, stream>>>(gw1, wTg1, 256, 128, n2);
        int n3 = 128 * 9 * 128;
        wt_kernel<<<(n3 + 255) / 256, 256, 0, stream>>>(gw2, wTg2, 128, 128, n3);
    }
    // 2. heatmap prep
    int totp = 2 * B * HW;
    prep_heatmaps<<<(totp + 255) / 256, 256, 0, stream>>>(hm_p, hm_i, hpn, hin, B, totp);
    // 3. cost volumes
    int totc = B * HW;
    cost_volume_kernel<<<(totc + 255) / 256, 256, 0, stream>>>(hpn, hin, cp, ci, B, totc);
    // 4. conv1 306->64 + relu (virtual concat) -> h
    {
        dim3 grid(12, 23, B);  // ceil(180/16), ceil(180/8), B * (64/64)
        conv3x3_kernel<1, true><<<grid, 256, 0, stream>>>(
            pts, cp, img, ci, wT1, fb1, hbuf, 306, 64, B);
    }
    // 5. conv2 64->4 + tanh*5 -> flow
    {
        dim3 grid(12, 12, B);
        conv_flow_kernel<<<grid, 256, 0, stream>>>(hbuf, fw2, fb2, flow, B);
    }
    // 6. grid sample -> fused_in
    int totg = 32 * B * HW;
    grid_sample_kernel<<<(totg + 255) / 256, 256, 0, stream>>>(pts, img, flow, fused, B, totg);
    // 7. g1 256->128 + relu
    {
        dim3 grid(12, 23, 2 * B);
        conv3x3_kernel<0, true><<<grid, 256, 0, stream>>>(
            fused, nullptr, nullptr, nullptr, wTg1, gb1, g1o, 256, 128, B);
    }
    // 8. g2 128->128 (no relu) -> out
    {
        dim3 grid(12, 23, 2 * B);
        conv3x3_kernel<0, false><<<grid, 256, 0, stream>>>(
            g1o, nullptr, nullptr, nullptr, wTg2, gb2, (float*)d_out, 128, 128, B);
    }
}

// Round 2
// 1036.136 us; speedup vs baseline: 2.9905x; 2.9905x over previous
//
#include <hip/hip_runtime.h>
#include <cstdint>

// ---------------------------------------------------------------------------
// SFA pipeline, round 2: MFMA bf16 convs (A single-bf16, W split hi+lo).
//   B=4, C=128, H=W=180, Q=5 -> feat_in=306(->320), hid=64
// Conv = implicit GEMM: M=16px(x), N=16oc, K=32ch per MFMA; 9 taps.
// Activations: halo-padded NHWC bf16 [B][194][194][CP], border zeroed.
// Weights: pre-baked frag-linear bf16 (hi,lo), read direct from L2.
// ---------------------------------------------------------------------------

constexpr int H = 180, W = 180, HW = H * W;
constexpr int PD = 194, PD2 = PD * PD;          // padded pixel grid

typedef __attribute__((ext_vector_type(8))) short short8;
typedef __attribute__((ext_vector_type(4))) float f32x4;

// ---- workspace layout (bytes) ---------------------------------------------
// R1: cat(96.35MB) then f2(77.1MB)   [cat dies after conv1; f2 born grid_sample]
// R2: hpn+hin(10.4) -> hbuf(33.2) -> go(38.5)
// R3: flow(2.07)   R4: weight frags (2.5)
constexpr size_t OFF_CAT  = 0;                          // ushort, B*PD2*320
constexpr size_t OFF_F2   = 0;                          // ushort, B*PD2*256
constexpr size_t R2       = 96348160;
constexpr size_t OFF_HPN  = R2;                         // float, 1296000
constexpr size_t OFF_HIN  = R2 + 5184000;               // float, 1296000
constexpr size_t OFF_HBUF = R2;                         // float, 8294400
constexpr size_t OFF_GO   = R2;                         // ushort, B*PD2*128
constexpr size_t R3       = R2 + 38539264;
constexpr size_t OFF_FLOW = R3;                         // float, 518400
constexpr size_t R4       = R3 + 2073600;
constexpr size_t OFF_WF1  = R4;                         // 720 KB
constexpr size_t OFF_WFG1 = R4 + 737280;                // 1152 KB
constexpr size_t OFF_WFG2 = R4 + 737280 + 1179648;      // 576 KB

__device__ __forceinline__ unsigned short f2bf(float x) {
    unsigned int u = __builtin_bit_cast(unsigned int, x);
    unsigned int r = (u + 0x7FFFu + ((u >> 16) & 1u)) >> 16;
    return (unsigned short)r;
}
__device__ __forceinline__ float bf2f(unsigned short b) {
    return __builtin_bit_cast(float, (unsigned int)b << 16);
}

#define GLL(SRC, DST) __builtin_amdgcn_global_load_lds(                        \
    (const __attribute__((address_space(1))) unsigned int*)(SRC),              \
    (__attribute__((address_space(3))) unsigned int*)(DST), 16, 0, 0)

// ---------------------------------------------------------------------------
// zero the halo border of a padded NHWC buffer (5236 border px per batch)
__global__ __launch_bounds__(256) void border_zero(unsigned short* __restrict__ buf,
                                                   int CPdiv8, int total) {
    int id = blockIdx.x * 256 + threadIdx.x;
    if (id >= total) return;
    int c8 = id % CPdiv8; int r = id / CPdiv8;
    int pi = r % 5236;    int b = r / 5236;
    int py, px;
    if (pi < 2716) { int ri = pi / 194; py = ri == 0 ? 0 : 180 + ri; px = pi % 194; }
    else { int j = pi - 2716; py = 1 + j / 14; int t = j % 14; px = t == 0 ? 0 : 180 + t; }
    short8 z = {0,0,0,0,0,0,0,0};
    *(short8*)&buf[((size_t)(b * PD + py) * PD + px) * (size_t)(CPdiv8 * 8) + c8 * 8] = z;
}

// ---------------------------------------------------------------------------
// build cat interior: pts -> ch 0..127, img -> ch 128..255 (perm!), zero 306..319
// (cp/ci go to 256..305 via cost_volume; weight transform applies the same perm)
__global__ __launch_bounds__(256) void build_cat(const float* __restrict__ pts,
                                                 const float* __restrict__ img,
                                                 unsigned short* __restrict__ cat) {
    int b = blockIdx.x / 180, h = blockIdx.x % 180;
    int t = threadIdx.x;
    if (t >= 180) return;
    char* pb = (char*)cat + ((size_t)(b * PD + 1 + h) * PD + (1 + t)) * 640;
    const float* ps = pts + (size_t)b * 128 * HW + h * W + t;
    const float* is = img + (size_t)b * 128 * HW + h * W + t;
#pragma unroll 4
    for (int cp = 0; cp < 64; ++cp) {
        float f0 = ps[(size_t)(2 * cp) * HW], f1 = ps[(size_t)(2 * cp + 1) * HW];
        *(unsigned int*)(pb + cp * 4) = (unsigned)f2bf(f0) | ((unsigned)f2bf(f1) << 16);
    }
#pragma unroll 4
    for (int cp = 0; cp < 64; ++cp) {
        float f0 = is[(size_t)(2 * cp) * HW], f1 = is[(size_t)(2 * cp + 1) * HW];
        *(unsigned int*)(pb + 256 + cp * 4) = (unsigned)f2bf(f0) | ((unsigned)f2bf(f1) << 16);
    }
#pragma unroll
    for (int j = 0; j < 7; ++j) *(unsigned int*)(pb + 612 + j * 4) = 0u;
}

// ---------------------------------------------------------------------------
// heatmap prep (unchanged): transpose (b,c,w,h)->(b,c,h,w), sigmoid, L2norm
__global__ __launch_bounds__(256) void prep_heatmaps(
    const float* __restrict__ hm_pts, const float* __restrict__ hm_img,
    float* __restrict__ hpn, float* __restrict__ hin, int B, int total) {
    int id = blockIdx.x * 256 + threadIdx.x;
    if (id >= total) return;
    int w = id % W; int r = id / W;
    int h = r % H;  r /= H;
    int b = r % B;  int tsel = r / B;
    const float* src = tsel ? hm_img : hm_pts;
    float* dst = tsel ? hin : hpn;
    float v[10]; float ss = 0.f;
#pragma unroll
    for (int c = 0; c < 10; ++c) {
        float x = src[((size_t)(b * 10 + c) * W + w) * H + h];
        float s = 1.f / (1.f + expf(-x));
        v[c] = s; ss += s * s;
    }
    float inv = 1.f / fmaxf(sqrtf(ss), 1e-12f);
#pragma unroll
    for (int c = 0; c < 10; ++c)
        dst[(size_t)(b * 10 + c) * HW + h * W + w] = v[c] * inv;
}

// ---------------------------------------------------------------------------
// cost volumes -> cat channels 256..280 (cp) and 281..305 (ci), bf16
__global__ __launch_bounds__(256) void cost_volume_cat(
    const float* __restrict__ hpn, const float* __restrict__ hin,
    unsigned short* __restrict__ cat, int B, int total) {
    int id = blockIdx.x * 256 + threadIdx.x;
    if (id >= total) return;
    int w = id % W; int r = id / W;
    int h = r % H;  int b = r / H;
    float hp_l[10], hi_l[10];
    size_t base = (size_t)b * 10 * HW + h * W + w;
#pragma unroll
    for (int c = 0; c < 10; ++c) {
        hp_l[c] = hpn[base + (size_t)c * HW];
        hi_l[c] = hin[base + (size_t)c * HW];
    }
    unsigned short* pb = cat + ((size_t)(b * PD + 1 + h) * PD + (1 + w)) * 320;
    int k = 0;
    for (int dy = 0; dy < 5; ++dy)
        for (int dx = 0; dx < 5; ++dx, ++k) {
            int yy = h + dy - 2, xx = w + dx - 2;
            float ap = 0.f, ai = 0.f;
            if (yy >= 0 && yy < H && xx >= 0 && xx < W) {
                size_t nb = (size_t)b * 10 * HW + yy * W + xx;
#pragma unroll
                for (int c = 0; c < 10; ++c) {
                    ap = fmaf(hp_l[c], hin[nb + (size_t)c * HW], ap);
                    ai = fmaf(hi_l[c], hpn[nb + (size_t)c * HW], ai);
                }
            }
            pb[256 + k] = f2bf(ap);
            pb[281 + k] = f2bf(ai);
        }
}

// ---------------------------------------------------------------------------
// weight frag transform: w fp32 [oc][Cin][3][3] -> frag-linear bf16 hi/lo.
// frag f = ((chunk*9+tap)*nOg + og)*2 + part; elem = f*512 + lane*8 + e.
// lane: oc = og*16 + (lane&15); c = chunk*32 + (lane>>4)*8 + e.
// MODE 1 (conv1): cat-channel -> ref-channel perm (img moved to 128..255).
template <int MODE>
__global__ __launch_bounds__(256) void wfrag_kernel(const float* __restrict__ w,
                                                    unsigned short* __restrict__ wf,
                                                    int Cin, int nOg, int nfrag) {
    int t = blockIdx.x * 256 + threadIdx.x;
    int f = t >> 6, lane = t & 63;
    if (f >= nfrag) return;
    int part = f & 1; int r = f >> 1;
    int og = r % nOg; r /= nOg;
    int tap = r % 9;  int chunk = r / 9;
    int oc = og * 16 + (lane & 15);
    short8 out;
#pragma unroll
    for (int e = 0; e < 8; ++e) {
        int c = chunk * 32 + ((lane >> 4) << 3) + e;
        int rc = c;
        if (MODE == 1) {
            if (c < 128) rc = c;
            else if (c < 256) rc = c + 25;        // img: cat 128.. -> ref 153..
            else if (c < 281) rc = c - 128;       // cp:  cat 256.. -> ref 128..
            else rc = c;                          // ci: 281..305 identical
        }
        float val = 0.f;
        if (rc < Cin && (MODE == 0 || c < 306))
            val = w[((size_t)oc * Cin + rc) * 9 + tap];
        unsigned short hi = f2bf(val);
        out[e] = (short)(part == 0 ? hi : f2bf(val - bf2f(hi)));
    }
    *(short8*)&wf[(size_t)f * 512 + lane * 8] = out;
}

// ---------------------------------------------------------------------------
// MFMA conv 3x3 SAME. Block: 256 thr = 4 waves; tile 16y x 16x x 64oc.
// Wave w: rows w*4..w*4+3. Per chunk(32ch): stage tile 18x18x32 bf16 via
// global_load_lds (linear); B-frags (wh+wl) direct from global (frag-linear).
template <int NCH, int COUT, int EPI, bool RELU>
__global__ __launch_bounds__(256, 2) void conv_mfma(
    const unsigned short* __restrict__ act,  // padded NHWC, CP = NCH*32
    const unsigned short* __restrict__ wf,
    const float* __restrict__ bias,
    float* __restrict__ outF,                // EPI 0: fp32 NCHW
    unsigned short* __restrict__ outB,       // EPI 1: padded NHWC bf16 (CP=COUT)
    int Bn) {
    constexpr int CP = NCH * 32;
    constexpr int NOG = COUT / 16;
    __shared__ __align__(16) char ldsAll[2 * 20736 + 8192];

    const int tid = threadIdx.x;
    const int lane = tid & 63, wv = tid >> 6;
    const int zz = blockIdx.z;
    const int bb = zz / (COUT / 64);
    const int oc0 = (zz % (COUT / 64)) * 64;
    const int og0 = oc0 >> 4;
    const int y0 = blockIdx.y * 16, x0 = blockIdx.x * 16;

    const char* actB = (const char*)act + (size_t)bb * PD2 * CP * 2;

    // staging source offsets (bytes within batch), chunk 0
    unsigned soff[6];
#pragma unroll
    for (int i = 0; i < 6; ++i) {
        int idx = i * 256 + tid;
        int p = idx >> 2, q = idx & 3;
        int yy = p / 18, xx = p % 18;
        soff[i] = ((unsigned)((y0 + yy) * PD + (x0 + xx)) * CP + q * 8) * 2;
    }
    const int alane = (lane & 15) * 32 + ((lane >> 4) << 3);

    f32x4 acc[4][4];
#pragma unroll
    for (int i = 0; i < 4; ++i)
#pragma unroll
        for (int j = 0; j < 4; ++j) acc[i][j] = (f32x4){0.f, 0.f, 0.f, 0.f};

    auto stage = [&](int chunk, int bsel) {
        unsigned co = (unsigned)chunk * 64;
#pragma unroll
        for (int i = 0; i < 5; ++i)
            GLL(actB + soff[i] + co,
                ldsAll + (size_t)bsel * 20736 + ((i << 8) + (wv << 6)) * 16);
        if (tid < 16)
            GLL(actB + soff[5] + co,
                ldsAll + (size_t)bsel * 20736 + ((5 << 8)) * 16);
    };

    stage(0, 0);
    asm volatile("s_waitcnt vmcnt(0)" ::: "memory");
    __syncthreads();

    int bsel = 0;
    for (int chunk = 0; chunk < NCH; ++chunk) {
        if (chunk + 1 < NCH) stage(chunk + 1, bsel ^ 1);
        const unsigned short* tb = (const unsigned short*)ldsAll + bsel * 10368;
#pragma unroll
        for (int tap = 0; tap < 9; ++tap) {
            const int dy = tap / 3, dx = tap % 3;
            const unsigned short* wfp =
                wf + ((size_t)((chunk * 9 + tap) * NOG + og0)) * 1024 + lane * 8;
            short8 bh[4], bl[4];
#pragma unroll
            for (int g = 0; g < 4; ++g) {
                bh[g] = *(const short8*)(wfp + g * 1024);
                bl[g] = *(const short8*)(wfp + g * 1024 + 512);
            }
#pragma unroll
            for (int rr = 0; rr < 4; ++rr) {
                const int yy = wv * 4 + rr + dy;
                short8 a = *(const short8*)(tb + (yy * 18 + dx) * 32 + alane);
#pragma unroll
                for (int g = 0; g < 4; ++g) {
                    asm("v_mfma_f32_16x16x32_bf16 %0, %1, %2, %0"
                        : "+v"(acc[rr][g]) : "v"(a), "v"(bh[g]));
                    asm("v_mfma_f32_16x16x32_bf16 %0, %1, %2, %0"
                        : "+v"(acc[rr][g]) : "v"(a), "v"(bl[g]));
                }
            }
        }
        asm volatile("s_waitcnt vmcnt(0)" ::: "memory");
        __syncthreads();
        bsel ^= 1;
    }

    // bias per lane
    float bv[4];
#pragma unroll
    for (int g = 0; g < 4; ++g) bv[g] = bias[oc0 + g * 16 + (lane & 15)];

    if constexpr (EPI == 0) {
        float* sc = (float*)(ldsAll + 41472 + wv * 2048);
#pragma unroll
        for (int rr = 0; rr < 4; ++rr) {
            const int yy = y0 + wv * 4 + rr;
#pragma unroll
            for (int g = 0; g < 4; ++g) {
                f32x4 v = acc[rr][g];
#pragma unroll
                for (int j = 0; j < 4; ++j) {
                    v[j] += bv[g];
                    if (RELU) v[j] = fmaxf(v[j], 0.f);
                }
                *(f32x4*)&sc[(lane & 15) * 20 + ((lane >> 4) << 2)] = v;
                asm volatile("s_waitcnt lgkmcnt(0)" ::: "memory");
                f32x4 rd = *(const f32x4*)&sc[(lane >> 2) * 20 + ((lane & 3) << 2)];
                const int oc = oc0 + g * 16 + (lane >> 2);
                const int xs = x0 + ((lane & 3) << 2);
                if (yy < H && xs < W)
                    *(f32x4*)&outF[((size_t)(bb * COUT + oc)) * HW + yy * W + xs] = rd;
                asm volatile("s_waitcnt lgkmcnt(0)" ::: "memory");
            }
        }
    } else {
        unsigned short* sb = (unsigned short*)(ldsAll + 41472 + wv * 2048);
#pragma unroll
        for (int rr = 0; rr < 4; ++rr) {
            const int yy = y0 + wv * 4 + rr;
#pragma unroll
            for (int g = 0; g < 4; ++g)
#pragma unroll
                for (int r2 = 0; r2 < 4; ++r2) {
                    float v = acc[rr][g][r2] + bv[g];
                    if (RELU) v = fmaxf(v, 0.f);
                    sb[(((lane >> 4) << 2) + r2) * 64 + g * 16 + (lane & 15)] = f2bf(v);
                }
            asm volatile("s_waitcnt lgkmcnt(0)" ::: "memory");
#pragma unroll
            for (int j = 0; j < 2; ++j) {
                int idx = j * 64 + lane;
                int px = idx >> 3, c8 = idx & 7;
                short8 rd = *(const short8*)&sb[px * 64 + c8 * 8];
                int gx = x0 + px;
                if (yy < H && gx < W)
                    *(short8*)&outB[((size_t)(bb * PD + 1 + yy) * PD + 1 + gx) * COUT
                                    + oc0 + c8 * 8] = rd;
            }
            asm volatile("s_waitcnt lgkmcnt(0)" ::: "memory");
        }
    }
}

// ---------------------------------------------------------------------------
// conv2 64->4 + tanh*5 -> flow (fp32, small). Block: 16x16 px.
__global__ __launch_bounds__(256) void conv_flow_kernel(
    const float* __restrict__ hbuf, const float* __restrict__ fw2,
    const float* __restrict__ fb2, float* __restrict__ flow, int B) {
    __shared__ __align__(16) float s_in[8][18][20];
    __shared__ __align__(16) float s_w[72][4];
    const int t = threadIdx.x;
    const int px = t & 15, py = t >> 4;
    const int b = blockIdx.z;
    const int ty0 = blockIdx.y * 16, tx0 = blockIdx.x * 16;
    float acc[4] = {0.f, 0.f, 0.f, 0.f};
    for (int chunk = 0; chunk < 8; ++chunk) {
        int c0 = chunk * 8;
        __syncthreads();
        for (int u = t; u < 8 * 18 * 18; u += 256) {
            int ch = u / 324, rem = u % 324;
            int row = rem / 18, col = rem % 18;
            int gy = ty0 + row - 1, gx = tx0 + col - 1;
            float v = 0.f;
            if (gy >= 0 && gy < H && gx >= 0 && gx < W)
                v = hbuf[(size_t)(b * 64 + c0 + ch) * HW + gy * W + gx];
            s_in[ch][row][col] = v;
        }
        for (int u = t; u < 288; u += 256) {
            int k = u >> 2, o = u & 3;
            int ch = k / 9, kk = k % 9;
            s_w[k][o] = fw2[(size_t)(o * 64 + c0 + ch) * 9 + kk];
        }
        __syncthreads();
#pragma unroll
        for (int ch = 0; ch < 8; ++ch)
#pragma unroll
            for (int ky = 0; ky < 3; ++ky)
#pragma unroll
                for (int kx = 0; kx < 3; ++kx) {
                    float a = s_in[ch][py + ky][px + kx];
                    const float4 w4 = *(const float4*)(&s_w[ch * 9 + ky * 3 + kx][0]);
                    acc[0] = fmaf(a, w4.x, acc[0]);
                    acc[1] = fmaf(a, w4.y, acc[1]);
                    acc[2] = fmaf(a, w4.z, acc[2]);
                    acc[3] = fmaf(a, w4.w, acc[3]);
                }
    }
    int y = ty0 + py, x = tx0 + px;
    if (y < H && x < W) {
#pragma unroll
        for (int o = 0; o < 4; ++o)
            flow[(size_t)(b * 4 + o) * HW + y * W + x] =
                tanhf(acc[o] + fb2[o]) * 5.0f;
    }
}

// ---------------------------------------------------------------------------
// grid sample (bilinear/border/align_corners) -> f2 padded NHWC bf16
// channels: 0..127 = aligned_i (img), 128..255 = aligned_p (pts)
__global__ __launch_bounds__(256) void grid_sample_bf(
    const float* __restrict__ pts, const float* __restrict__ img,
    const float* __restrict__ flow, unsigned short* __restrict__ f2,
    int B, int total) {
    int id = blockIdx.x * 256 + threadIdx.x;
    if (id >= total) return;                 // total = 32*B*HW
    int w = id % W; int r = id / W;
    int h = r % H;  r /= H;
    int b = r % B;  int q = r / B;
    const bool is_img = q < 16;
    const int cb = (is_img ? q : q - 16) * 8;
    const float* src = is_img ? img : pts;
    const int fo = is_img ? 2 : 0;
    size_t fbase = (size_t)b * 4 * HW + h * W + w;
    float sx = (float)w + flow[fbase + (size_t)fo * HW];
    float sy = (float)h + flow[fbase + (size_t)(fo + 1) * HW];
    sx = fminf(fmaxf(sx, 0.f), (float)(W - 1));
    sy = fminf(fmaxf(sy, 0.f), (float)(H - 1));
    float x0f = floorf(sx), y0f = floorf(sy);
    float x1f = fminf(x0f + 1.f, (float)(W - 1));
    float y1f = fminf(y0f + 1.f, (float)(H - 1));
    float wx = sx - x0f, wy = sy - y0f;
    int x0 = (int)x0f, x1 = (int)x1f, y0 = (int)y0f, y1 = (int)y1f;
    float w00 = (1.f - wx) * (1.f - wy), w01 = wx * (1.f - wy);
    float w10 = (1.f - wx) * wy,         w11 = wx * wy;
    const float* sbp = src + (size_t)b * 128 * HW;
    short8 pack;
#pragma unroll
    for (int j = 0; j < 8; ++j) {
        const float* p = sbp + (size_t)(cb + j) * HW;
        float v = p[y0 * W + x0] * w00 + p[y0 * W + x1] * w01 +
                  p[y1 * W + x0] * w10 + p[y1 * W + x1] * w11;
        pack[j] = (short)f2bf(v);
    }
    *(short8*)&f2[((size_t)(b * PD + 1 + h) * PD + 1 + w) * 256 +
                  (is_img ? 0 : 128) + cb] = pack;
}

// ---------------------------------------------------------------------------
extern "C" void kernel_launch(void* const* d_in, const int* in_sizes, int n_in,
                              void* d_out, int out_size, void* d_ws, size_t ws_size,
                              hipStream_t stream) {
    const float* pts  = (const float*)d_in[0];
    const float* img  = (const float*)d_in[1];
    const float* hm_p = (const float*)d_in[2];
    const float* hm_i = (const float*)d_in[3];
    const float* fw1  = (const float*)d_in[4];
    const float* fb1  = (const float*)d_in[5];
    const float* fw2  = (const float*)d_in[6];
    const float* fb2  = (const float*)d_in[7];
    const float* gw1  = (const float*)d_in[8];
    const float* gb1  = (const float*)d_in[9];
    const float* gw2  = (const float*)d_in[10];
    const float* gb2  = (const float*)d_in[11];
    char* ws = (char*)d_ws;
    const int B = in_sizes[0] / (128 * HW);   // 4

    unsigned short* cat  = (unsigned short*)(ws + OFF_CAT);
    unsigned short* f2   = (unsigned short*)(ws + OFF_F2);
    unsigned short* go   = (unsigned short*)(ws + OFF_GO);
    float* hpn   = (float*)(ws + OFF_HPN);
    float* hin   = (float*)(ws + OFF_HIN);
    float* hbuf  = (float*)(ws + OFF_HBUF);
    float* flow  = (float*)(ws + OFF_FLOW);
    unsigned short* wf1  = (unsigned short*)(ws + OFF_WF1);
    unsigned short* wfg1 = (unsigned short*)(ws + OFF_WFG1);
    unsigned short* wfg2 = (unsigned short*)(ws + OFF_WFG2);

    // 1. weight frag transforms
    wfrag_kernel<1><<<180, 256, 0, stream>>>(fw1, wf1, 306, 4, 720);
    wfrag_kernel<0><<<288, 256, 0, stream>>>(gw1, wfg1, 256, 8, 1152);
    wfrag_kernel<0><<<144, 256, 0, stream>>>(gw2, wfg2, 128, 8, 576);
    // 2. cat halo zero + interior build
    {
        int tot = B * 5236 * 40;
        border_zero<<<(tot + 255) / 256, 256, 0, stream>>>(cat, 40, tot);
    }
    build_cat<<<B * 180, 256, 0, stream>>>(pts, img, cat);
    // 3. heatmaps + cost volumes
    int totp = 2 * B * HW;
    prep_heatmaps<<<(totp + 255) / 256, 256, 0, stream>>>(hm_p, hm_i, hpn, hin, B, totp);
    int totc = B * HW;
    cost_volume_cat<<<(totc + 255) / 256, 256, 0, stream>>>(hpn, hin, cat, B, totc);
    // 4. conv1 320->64 + relu -> hbuf (fp32 NCHW)
    {
        dim3 grid(12, 12, B);
        conv_mfma<10, 64, 0, true><<<grid, 256, 0, stream>>>(
            cat, wf1, fb1, hbuf, nullptr, B);
    }
    // 5. conv2 64->4 + tanh*5 -> flow
    {
        dim3 grid(12, 12, B);
        conv_flow_kernel<<<grid, 256, 0, stream>>>(hbuf, fw2, fb2, flow, B);
    }
    // 6. halo zeros for f2/go (after hbuf/cat consumers; regions alias them)
    {
        int tot = B * 5236 * 32;
        border_zero<<<(tot + 255) / 256, 256, 0, stream>>>(f2, 32, tot);
        int tot2 = B * 5236 * 16;
        border_zero<<<(tot2 + 255) / 256, 256, 0, stream>>>(go, 16, tot2);
    }
    // 7. grid sample -> f2 interior
    int totg = 32 * B * HW;
    grid_sample_bf<<<(totg + 255) / 256, 256, 0, stream>>>(pts, img, flow, f2, B, totg);
    // 8. g1 256->128 + relu -> go (padded NHWC bf16)
    {
        dim3 grid(12, 12, 2 * B);
        conv_mfma<8, 128, 1, true><<<grid, 256, 0, stream>>>(
            f2, wfg1, gb1, nullptr, go, B);
    }
    // 9. g2 128->128 -> d_out (fp32 NCHW)
    {
        dim3 grid(12, 12, 2 * B);
        conv_mfma<4, 128, 0, false><<<grid, 256, 0, stream>>>(
            go, wfg2, gb2, (float*)d_out, nullptr, B);
    }
}

// Round 3
// 807.139 us; speedup vs baseline: 3.8389x; 1.2837x over previous
//
#include <hip/hip_runtime.h>
#include <cstdint>

// ---------------------------------------------------------------------------
// SFA pipeline, round 3: MFMA convs with software-pipelined weight prefetch.
//   B=4, C=128, H=W=180, Q=5 -> feat_in=306(->320), hid=64
// Conv = implicit GEMM: M=16px(x), N=16oc, K=32ch per MFMA; 9 taps.
// Activations: halo-padded NHWC bf16 [B][194][194][CP], border zeroed.
// Weights: pre-baked frag-linear bf16 (hi,lo), double-buffered in VGPRs.
// ---------------------------------------------------------------------------

constexpr int H = 180, W = 180, HW = H * W;
constexpr int PD = 194, PD2 = PD * PD;          // padded pixel grid

typedef __attribute__((ext_vector_type(8))) short short8;
typedef __attribute__((ext_vector_type(4))) float f32x4;

// ---- workspace layout (bytes) ---------------------------------------------
constexpr size_t OFF_CAT  = 0;                          // ushort, B*PD2*320
constexpr size_t OFF_F2   = 0;                          // ushort, B*PD2*256
constexpr size_t R2       = 96348160;
constexpr size_t OFF_HPN  = R2;                         // float, 1296000
constexpr size_t OFF_HIN  = R2 + 5184000;               // float, 1296000
constexpr size_t OFF_HBUF = R2;                         // float, 8294400
constexpr size_t OFF_GO   = R2;                         // ushort, B*PD2*128
constexpr size_t R3       = R2 + 38539264;
constexpr size_t OFF_FLOW = R3;                         // float, 518400
constexpr size_t R4       = R3 + 2073600;
constexpr size_t OFF_WF1  = R4;                         // 720 KB
constexpr size_t OFF_WFG1 = R4 + 737280;                // 1152 KB
constexpr size_t OFF_WFG2 = R4 + 737280 + 1179648;      // 576 KB

__device__ __forceinline__ unsigned short f2bf(float x) {
    unsigned int u = __builtin_bit_cast(unsigned int, x);
    unsigned int r = (u + 0x7FFFu + ((u >> 16) & 1u)) >> 16;
    return (unsigned short)r;
}
__device__ __forceinline__ float bf2f(unsigned short b) {
    return __builtin_bit_cast(float, (unsigned int)b << 16);
}

#define GLL(SRC, DST) __builtin_amdgcn_global_load_lds(                        \
    (const __attribute__((address_space(1))) unsigned int*)(SRC),              \
    (__attribute__((address_space(3))) unsigned int*)(DST), 16, 0, 0)

// ---------------------------------------------------------------------------
// zero the halo border of a padded NHWC buffer (5236 border px per batch)
__global__ __launch_bounds__(256) void border_zero(unsigned short* __restrict__ buf,
                                                   int CPdiv8, int total) {
    int id = blockIdx.x * 256 + threadIdx.x;
    if (id >= total) return;
    int c8 = id % CPdiv8; int r = id / CPdiv8;
    int pi = r % 5236;    int b = r / 5236;
    int py, px;
    if (pi < 2716) { int ri = pi / 194; py = ri == 0 ? 0 : 180 + ri; px = pi % 194; }
    else { int j = pi - 2716; py = 1 + j / 14; int t = j % 14; px = t == 0 ? 0 : 180 + t; }
    short8 z = {0,0,0,0,0,0,0,0};
    *(short8*)&buf[((size_t)(b * PD + py) * PD + px) * (size_t)(CPdiv8 * 8) + c8 * 8] = z;
}

// ---------------------------------------------------------------------------
// build cat interior: pts -> ch 0..127, img -> ch 128..255 (perm; weights match)
__global__ __launch_bounds__(192) void build_cat(const float* __restrict__ pts,
                                                 const float* __restrict__ img,
                                                 unsigned short* __restrict__ cat) {
    int b = blockIdx.x / 180, h = blockIdx.x % 180;
    int t = threadIdx.x;
    if (t >= 180) return;
    unsigned short* pb = cat + ((size_t)(b * PD + 1 + h) * PD + (1 + t)) * 320;
    const float* ps = pts + (size_t)b * 128 * HW + h * W + t;
    const float* is = img + (size_t)b * 128 * HW + h * W + t;
#pragma unroll 4
    for (int v = 0; v < 16; ++v) {
        short8 o;
#pragma unroll
        for (int e = 0; e < 8; ++e) o[e] = (short)f2bf(ps[(size_t)(v * 8 + e) * HW]);
        *(short8*)&pb[v * 8] = o;
    }
#pragma unroll 4
    for (int v = 0; v < 16; ++v) {
        short8 o;
#pragma unroll
        for (int e = 0; e < 8; ++e) o[e] = (short)f2bf(is[(size_t)(v * 8 + e) * HW]);
        *(short8*)&pb[128 + v * 8] = o;
    }
}

// ---------------------------------------------------------------------------
// heatmap prep, LDS-tiled: coalesced transposed reads + coalesced writes.
// grid (12, 12, 2*B); block 256.  src (b,c,w,h) -> dst (b,c,h,w) NCHW fp32.
__global__ __launch_bounds__(256) void prep_heatmaps(
    const float* __restrict__ hm_pts, const float* __restrict__ hm_img,
    float* __restrict__ hpn, float* __restrict__ hin, int B) {
    __shared__ float s[10][16][17];          // [c][w][h+pad]
    const int t = threadIdx.x;
    const int tsel = blockIdx.z & 1, b = blockIdx.z >> 1;
    const int h0 = blockIdx.y * 16, w0 = blockIdx.x * 16;
    const float* src = tsel ? hm_img : hm_pts;
    float* dst = tsel ? hin : hpn;
    {
        const int th = t & 15, tw = t >> 4;
        const int gh = h0 + th, gw = w0 + tw;
        if (gh < H && gw < W) {
#pragma unroll
            for (int c = 0; c < 10; ++c)
                s[c][tw][th] = src[((size_t)(b * 10 + c) * W + gw) * H + gh];
        }
    }
    __syncthreads();
    const int wq = t & 15, hq = t >> 4;
    const int gh = h0 + hq, gw = w0 + wq;
    if (gh >= H || gw >= W) return;
    float v[10]; float ss = 0.f;
#pragma unroll
    for (int c = 0; c < 10; ++c) {
        float x = s[c][wq][hq];
        float sg = 1.f / (1.f + expf(-x));
        v[c] = sg; ss += sg * sg;
    }
    float inv = 1.f / fmaxf(sqrtf(ss), 1e-12f);
#pragma unroll
    for (int c = 0; c < 10; ++c)
        dst[(size_t)(b * 10 + c) * HW + gh * W + gw] = v[c] * inv;
}

// ---------------------------------------------------------------------------
// cost volumes -> cat channels 256..280 (cp), 281..305 (ci), 306..319 zero.
// Vectorized: 8 x 16B stores per pixel (was 50 scalar ushort stores).
__global__ __launch_bounds__(256) void cost_volume_cat(
    const float* __restrict__ hpn, const float* __restrict__ hin,
    unsigned short* __restrict__ cat, int B, int total) {
    int id = blockIdx.x * 256 + threadIdx.x;
    if (id >= total) return;
    int w = id % W; int r = id / W;
    int h = r % H;  int b = r / H;
    float hp_l[10], hi_l[10];
    size_t base = (size_t)b * 10 * HW + h * W + w;
#pragma unroll
    for (int c = 0; c < 10; ++c) {
        hp_l[c] = hpn[base + (size_t)c * HW];
        hi_l[c] = hin[base + (size_t)c * HW];
    }
    unsigned pk[32];
#pragma unroll
    for (int j = 0; j < 32; ++j) pk[j] = 0;
#pragma unroll
    for (int dy = 0; dy < 5; ++dy)
#pragma unroll
        for (int dx = 0; dx < 5; ++dx) {
            const int k = dy * 5 + dx;
            int yy = h + dy - 2, xx = w + dx - 2;
            float ap = 0.f, ai = 0.f;
            if (yy >= 0 && yy < H && xx >= 0 && xx < W) {
                size_t nb = (size_t)b * 10 * HW + yy * W + xx;
#pragma unroll
                for (int c = 0; c < 10; ++c) {
                    ap = fmaf(hp_l[c], hin[nb + (size_t)c * HW], ap);
                    ai = fmaf(hi_l[c], hpn[nb + (size_t)c * HW], ai);
                }
            }
            pk[k >> 1] |= (unsigned)f2bf(ap) << ((k & 1) * 16);
            const int kc = 25 + k;
            pk[kc >> 1] |= (unsigned)f2bf(ai) << ((kc & 1) * 16);
        }
    unsigned short* pb = cat + ((size_t)(b * PD + 1 + h) * PD + (1 + w)) * 320 + 256;
#pragma unroll
    for (int v = 0; v < 8; ++v) {
        uint4 q = {pk[v * 4], pk[v * 4 + 1], pk[v * 4 + 2], pk[v * 4 + 3]};
        *(uint4*)((char*)pb + v * 16) = q;
    }
}

// ---------------------------------------------------------------------------
// weight frag transform: w fp32 [oc][Cin][3][3] -> frag-linear bf16 hi/lo.
template <int MODE>
__global__ __launch_bounds__(256) void wfrag_kernel(const float* __restrict__ w,
                                                    unsigned short* __restrict__ wf,
                                                    int Cin, int nOg, int nfrag) {
    int t = blockIdx.x * 256 + threadIdx.x;
    int f = t >> 6, lane = t & 63;
    if (f >= nfrag) return;
    int part = f & 1; int r = f >> 1;
    int og = r % nOg; r /= nOg;
    int tap = r % 9;  int chunk = r / 9;
    int oc = og * 16 + (lane & 15);
    short8 out;
#pragma unroll
    for (int e = 0; e < 8; ++e) {
        int c = chunk * 32 + ((lane >> 4) << 3) + e;
        int rc = c;
        if (MODE == 1) {
            if (c < 128) rc = c;
            else if (c < 256) rc = c + 25;
            else if (c < 281) rc = c - 128;
            else rc = c;
        }
        float val = 0.f;
        if (rc < Cin && (MODE == 0 || c < 306))
            val = w[((size_t)oc * Cin + rc) * 9 + tap];
        unsigned short hi = f2bf(val);
        out[e] = (short)(part == 0 ? hi : f2bf(val - bf2f(hi)));
    }
    *(short8*)&wf[(size_t)f * 512 + lane * 8] = out;
}

// ---------------------------------------------------------------------------
// MFMA conv 3x3 SAME, software-pipelined weights.
// Block: 256 thr = 4 waves; tile 16y x 16x x OCB oc. Wave wv: rows wv*4..+3.
template <int NCH, int COUT, int EPI, bool RELU, int OCB>
__global__ __launch_bounds__(256, 2) void conv_mfma(
    const unsigned short* __restrict__ act,  // padded NHWC, CP = NCH*32
    const unsigned short* __restrict__ wf,
    const float* __restrict__ bias,
    float* __restrict__ outF,                // EPI 0: fp32 NCHW
    unsigned short* __restrict__ outB,       // EPI 1: padded NHWC bf16 (CP=COUT)
    int Bn) {
    constexpr int CP = NCH * 32;
    constexpr int NOG = COUT / 16;           // frag-layout og stride
    constexpr int G = OCB / 16;              // og groups per block
    __shared__ __align__(16) char ldsAll[2 * 20736 + 8192];

    const int tid = threadIdx.x;
    const int lane = tid & 63, wv = tid >> 6;
    const int zz = blockIdx.z;
    constexpr int NT = COUT / OCB;
    const int bb = zz / NT;
    const int oc0 = (zz % NT) * OCB;
    const int og0 = oc0 >> 4;
    const int y0 = blockIdx.y * 16, x0 = blockIdx.x * 16;

    const char* actB = (const char*)act + (size_t)bb * PD2 * CP * 2;

    unsigned soff[6];
#pragma unroll
    for (int i = 0; i < 6; ++i) {
        int idx = i * 256 + tid;
        int p = idx >> 2, q = idx & 3;
        int yy = p / 18, xx = p % 18;
        soff[i] = ((unsigned)((y0 + yy) * PD + (x0 + xx)) * CP + q * 8) * 2;
    }
    const int alane = (lane & 15) * 32 + ((lane >> 4) << 3);
    const unsigned short* wlane = wf + (size_t)og0 * 1024 + lane * 8;

    f32x4 acc[4][G];
#pragma unroll
    for (int i = 0; i < 4; ++i)
#pragma unroll
        for (int j = 0; j < G; ++j) acc[i][j] = (f32x4){0.f, 0.f, 0.f, 0.f};

    auto stage = [&](int chunk, int bsel) {
        unsigned co = (unsigned)chunk * 64;
#pragma unroll
        for (int i = 0; i < 5; ++i)
            GLL(actB + soff[i] + co,
                ldsAll + (size_t)bsel * 20736 + ((i << 8) + (wv << 6)) * 16);
        if (tid < 16)
            GLL(actB + soff[5] + co,
                ldsAll + (size_t)bsel * 20736 + ((5 << 8)) * 16);
    };
    auto loadW = [&](int idx, short8 (&dh)[G], short8 (&dl)[G]) {
        const unsigned short* p = wlane + (size_t)idx * NOG * 1024;
#pragma unroll
        for (int g = 0; g < G; ++g) {
            dh[g] = *(const short8*)(p + g * 1024);
            dl[g] = *(const short8*)(p + g * 1024 + 512);
        }
    };
    auto compTap = [&](int dy, int dx, const short8 (&bh)[G], const short8 (&bl)[G],
                       const unsigned short* tb) {
        __builtin_amdgcn_s_setprio(1);
#pragma unroll
        for (int rr = 0; rr < 4; ++rr) {
            const int yy = wv * 4 + rr + dy;
            short8 a = *(const short8*)(tb + (yy * 18 + dx) * 32 + alane);
#pragma unroll
            for (int g = 0; g < G; ++g) {
                asm("v_mfma_f32_16x16x32_bf16 %0, %1, %2, %0"
                    : "+v"(acc[rr][g]) : "v"(a), "v"(bh[g]));
                asm("v_mfma_f32_16x16x32_bf16 %0, %1, %2, %0"
                    : "+v"(acc[rr][g]) : "v"(a), "v"(bl[g]));
            }
        }
        __builtin_amdgcn_s_setprio(0);
    };

    short8 wh[2][G], wl[2][G];
    stage(0, 0);
    loadW(0, wh[0], wl[0]);                 // w[chunk0, tap0] -> buf0
    asm volatile("s_waitcnt vmcnt(0)" ::: "memory");
    __syncthreads();

    int bsel = 0;
    for (int cp2 = 0; cp2 < NCH / 2; ++cp2) {
#pragma unroll
        for (int par = 0; par < 2; ++par) {
            const int chunk = cp2 * 2 + par;
            const unsigned short* tb = (const unsigned short*)ldsAll + bsel * 10368;
#pragma unroll
            for (int t = 0; t < 9; ++t) {
                const int cb = (t + par) & 1;       // current weight buf
                // prefetch next tap's weights into the other buf
                if (t < 8) {
                    if (cb) loadW(chunk * 9 + t + 1, wh[0], wl[0]);
                    else    loadW(chunk * 9 + t + 1, wh[1], wl[1]);
                } else if (chunk + 1 < NCH) {
                    if (cb) loadW((chunk + 1) * 9, wh[0], wl[0]);
                    else    loadW((chunk + 1) * 9, wh[1], wl[1]);
                }
                if (t == 0 && chunk + 1 < NCH) stage(chunk + 1, bsel ^ 1);
                if (cb) compTap(t / 3, t % 3, wh[1], wl[1], tb);
                else    compTap(t / 3, t % 3, wh[0], wl[0], tb);
            }
            asm volatile("s_waitcnt vmcnt(0)" ::: "memory");
            __syncthreads();
            bsel ^= 1;
        }
    }

    float bv[G];
#pragma unroll
    for (int g = 0; g < G; ++g) bv[g] = bias[oc0 + g * 16 + (lane & 15)];

    if constexpr (EPI == 0) {
        float* sc = (float*)(ldsAll + 41472 + wv * 2048);
#pragma unroll
        for (int rr = 0; rr < 4; ++rr) {
            const int yy = y0 + wv * 4 + rr;
#pragma unroll
            for (int g = 0; g < G; ++g) {
                f32x4 v = acc[rr][g];
#pragma unroll
                for (int j = 0; j < 4; ++j) {
                    v[j] += bv[g];
                    if (RELU) v[j] = fmaxf(v[j], 0.f);
                }
                *(f32x4*)&sc[(lane & 15) * 20 + ((lane >> 4) << 2)] = v;
                asm volatile("s_waitcnt lgkmcnt(0)" ::: "memory");
                f32x4 rd = *(const f32x4*)&sc[(lane >> 2) * 20 + ((lane & 3) << 2)];
                const int oc = oc0 + g * 16 + (lane >> 2);
                const int xs = x0 + ((lane & 3) << 2);
                if (yy < H && xs < W)
                    *(f32x4*)&outF[((size_t)(bb * COUT + oc)) * HW + yy * W + xs] = rd;
                asm volatile("s_waitcnt lgkmcnt(0)" ::: "memory");
            }
        }
    } else {
        unsigned short* sb = (unsigned short*)(ldsAll + 41472 + wv * 2048);
#pragma unroll
        for (int rr = 0; rr < 4; ++rr) {
            const int yy = y0 + wv * 4 + rr;
#pragma unroll
            for (int g = 0; g < G; ++g)
#pragma unroll
                for (int r2 = 0; r2 < 4; ++r2) {
                    float v = acc[rr][g][r2] + bv[g];
                    if (RELU) v = fmaxf(v, 0.f);
                    sb[(((lane >> 4) << 2) + r2) * OCB + g * 16 + (lane & 15)] = f2bf(v);
                }
            asm volatile("s_waitcnt lgkmcnt(0)" ::: "memory");
#pragma unroll
            for (int j = 0; j < OCB / 32; ++j) {
                int idx = j * 64 + lane;
                int px = idx / (OCB / 8), c8 = idx % (OCB / 8);
                short8 rd = *(const short8*)&sb[px * OCB + c8 * 8];
                int gx = x0 + px;
                if (yy < H && gx < W)
                    *(short8*)&outB[((size_t)(bb * PD + 1 + yy) * PD + 1 + gx) * COUT
                                    + oc0 + c8 * 8] = rd;
            }
            asm volatile("s_waitcnt lgkmcnt(0)" ::: "memory");
        }
    }
}

// ---------------------------------------------------------------------------
// conv2 64->4 + tanh*5 -> flow (fp32, small). Block: 16x16 px.
__global__ __launch_bounds__(256) void conv_flow_kernel(
    const float* __restrict__ hbuf, const float* __restrict__ fw2,
    const float* __restrict__ fb2, float* __restrict__ flow, int B) {
    __shared__ __align__(16) float s_in[8][18][20];
    __shared__ __align__(16) float s_w[72][4];
    const int t = threadIdx.x;
    const int px = t & 15, py = t >> 4;
    const int b = blockIdx.z;
    const int ty0 = blockIdx.y * 16, tx0 = blockIdx.x * 16;
    float acc[4] = {0.f, 0.f, 0.f, 0.f};
    for (int chunk = 0; chunk < 8; ++chunk) {
        int c0 = chunk * 8;
        __syncthreads();
        for (int u = t; u < 8 * 18 * 18; u += 256) {
            int ch = u / 324, rem = u % 324;
            int row = rem / 18, col = rem % 18;
            int gy = ty0 + row - 1, gx = tx0 + col - 1;
            float v = 0.f;
            if (gy >= 0 && gy < H && gx >= 0 && gx < W)
                v = hbuf[(size_t)(b * 64 + c0 + ch) * HW + gy * W + gx];
            s_in[ch][row][col] = v;
        }
        for (int u = t; u < 288; u += 256) {
            int k = u >> 2, o = u & 3;
            int ch = k / 9, kk = k % 9;
            s_w[k][o] = fw2[(size_t)(o * 64 + c0 + ch) * 9 + kk];
        }
        __syncthreads();
#pragma unroll
        for (int ch = 0; ch < 8; ++ch)
#pragma unroll
            for (int ky = 0; ky < 3; ++ky)
#pragma unroll
                for (int kx = 0; kx < 3; ++kx) {
                    float a = s_in[ch][py + ky][px + kx];
                    const float4 w4 = *(const float4*)(&s_w[ch * 9 + ky * 3 + kx][0]);
                    acc[0] = fmaf(a, w4.x, acc[0]);
                    acc[1] = fmaf(a, w4.y, acc[1]);
                    acc[2] = fmaf(a, w4.z, acc[2]);
                    acc[3] = fmaf(a, w4.w, acc[3]);
                }
    }
    int y = ty0 + py, x = tx0 + px;
    if (y < H && x < W) {
#pragma unroll
        for (int o = 0; o < 4; ++o)
            flow[(size_t)(b * 4 + o) * HW + y * W + x] =
                tanhf(acc[o] + fb2[o]) * 5.0f;
    }
}

// ---------------------------------------------------------------------------
// grid sample (bilinear/border/align_corners) -> f2 padded NHWC bf16
__global__ __launch_bounds__(256) void grid_sample_bf(
    const float* __restrict__ pts, const float* __restrict__ img,
    const float* __restrict__ flow, unsigned short* __restrict__ f2,
    int B, int total) {
    int id = blockIdx.x * 256 + threadIdx.x;
    if (id >= total) return;                 // total = 32*B*HW
    int w = id % W; int r = id / W;
    int h = r % H;  r /= H;
    int b = r % B;  int q = r / B;
    const bool is_img = q < 16;
    const int cb = (is_img ? q : q - 16) * 8;
    const float* src = is_img ? img : pts;
    const int fo = is_img ? 2 : 0;
    size_t fbase = (size_t)b * 4 * HW + h * W + w;
    float sx = (float)w + flow[fbase + (size_t)fo * HW];
    float sy = (float)h + flow[fbase + (size_t)(fo + 1) * HW];
    sx = fminf(fmaxf(sx, 0.f), (float)(W - 1));
    sy = fminf(fmaxf(sy, 0.f), (float)(H - 1));
    float x0f = floorf(sx), y0f = floorf(sy);
    float x1f = fminf(x0f + 1.f, (float)(W - 1));
    float y1f = fminf(y0f + 1.f, (float)(H - 1));
    float wx = sx - x0f, wy = sy - y0f;
    int x0 = (int)x0f, x1 = (int)x1f, y0 = (int)y0f, y1 = (int)y1f;
    float w00 = (1.f - wx) * (1.f - wy), w01 = wx * (1.f - wy);
    float w10 = (1.f - wx) * wy,         w11 = wx * wy;
    const float* sbp = src + (size_t)b * 128 * HW;
    short8 pack;
#pragma unroll
    for (int j = 0; j < 8; ++j) {
        const float* p = sbp + (size_t)(cb + j) * HW;
        float v = p[y0 * W + x0] * w00 + p[y0 * W + x1] * w01 +
                  p[y1 * W + x0] * w10 + p[y1 * W + x1] * w11;
        pack[j] = (short)f2bf(v);
    }
    *(short8*)&f2[((size_t)(b * PD + 1 + h) * PD + 1 + w) * 256 +
                  (is_img ? 0 : 128) + cb] = pack;
}

// ---------------------------------------------------------------------------
extern "C" void kernel_launch(void* const* d_in, const int* in_sizes, int n_in,
                              void* d_out, int out_size, void* d_ws, size_t ws_size,
                              hipStream_t stream) {
    const float* pts  = (const float*)d_in[0];
    const float* img  = (const float*)d_in[1];
    const float* hm_p = (const float*)d_in[2];
    const float* hm_i = (const float*)d_in[3];
    const float* fw1  = (const float*)d_in[4];
    const float* fb1  = (const float*)d_in[5];
    const float* fw2  = (const float*)d_in[6];
    const float* fb2  = (const float*)d_in[7];
    const float* gw1  = (const float*)d_in[8];
    const float* gb1  = (const float*)d_in[9];
    const float* gw2  = (const float*)d_in[10];
    const float* gb2  = (const float*)d_in[11];
    char* ws = (char*)d_ws;
    const int B = in_sizes[0] / (128 * HW);   // 4

    unsigned short* cat  = (unsigned short*)(ws + OFF_CAT);
    unsigned short* f2   = (unsigned short*)(ws + OFF_F2);
    unsigned short* go   = (unsigned short*)(ws + OFF_GO);
    float* hpn   = (float*)(ws + OFF_HPN);
    float* hin   = (float*)(ws + OFF_HIN);
    float* hbuf  = (float*)(ws + OFF_HBUF);
    float* flow  = (float*)(ws + OFF_FLOW);
    unsigned short* wf1  = (unsigned short*)(ws + OFF_WF1);
    unsigned short* wfg1 = (unsigned short*)(ws + OFF_WFG1);
    unsigned short* wfg2 = (unsigned short*)(ws + OFF_WFG2);

    // 1. weight frag transforms
    wfrag_kernel<1><<<180, 256, 0, stream>>>(fw1, wf1, 306, 4, 720);
    wfrag_kernel<0><<<288, 256, 0, stream>>>(gw1, wfg1, 256, 8, 1152);
    wfrag_kernel<0><<<144, 256, 0, stream>>>(gw2, wfg2, 128, 8, 576);
    // 2. cat halo zero + interior build
    {
        int tot = B * 5236 * 40;
        border_zero<<<(tot + 255) / 256, 256, 0, stream>>>(cat, 40, tot);
    }
    build_cat<<<B * 180, 192, 0, stream>>>(pts, img, cat);
    // 3. heatmaps + cost volumes
    {
        dim3 grid(12, 12, 2 * B);
        prep_heatmaps<<<grid, 256, 0, stream>>>(hm_p, hm_i, hpn, hin, B);
    }
    int totc = B * HW;
    cost_volume_cat<<<(totc + 255) / 256, 256, 0, stream>>>(hpn, hin, cat, B, totc);
    // 4. conv1 320->64 + relu -> hbuf (fp32 NCHW); OCB=32 for tail
    {
        dim3 grid(12, 12, 2 * B);
        conv_mfma<10, 64, 0, true, 32><<<grid, 256, 0, stream>>>(
            cat, wf1, fb1, hbuf, nullptr, B);
    }
    // 5. conv2 64->4 + tanh*5 -> flow
    {
        dim3 grid(12, 12, B);
        conv_flow_kernel<<<grid, 256, 0, stream>>>(hbuf, fw2, fb2, flow, B);
    }
    // 6. halo zeros for f2/go
    {
        int tot = B * 5236 * 32;
        border_zero<<<(tot + 255) / 256, 256, 0, stream>>>(f2, 32, tot);
        int tot2 = B * 5236 * 16;
        border_zero<<<(tot2 + 255) / 256, 256, 0, stream>>>(go, 16, tot2);
    }
    // 7. grid sample -> f2 interior
    int totg = 32 * B * HW;
    grid_sample_bf<<<(totg + 255) / 256, 256, 0, stream>>>(pts, img, flow, f2, B, totg);
    // 8. g1 256->128 + relu -> go (padded NHWC bf16)
    {
        dim3 grid(12, 12, 2 * B);
        conv_mfma<8, 128, 1, true, 64><<<grid, 256, 0, stream>>>(
            f2, wfg1, gb1, nullptr, go, B);
    }
    // 9. g2 128->128 -> d_out (fp32 NCHW)
    {
        dim3 grid(12, 12, 2 * B);
        conv_mfma<4, 128, 0, false, 64><<<grid, 256, 0, stream>>>(
            go, wfg2, gb2, (float*)d_out, nullptr, B);
    }
}